// Round 1
// baseline (13745.197 us; speedup 1.0000x reference)
//
#include <hip/hip_runtime.h>

#define NW 20000
#define NE 30000
#define ER 200000
#define EE 200000
#define H 512
#define MDIM 512
#define ECH 4101
#define OUT_DIM 250
#define NLAYER 4
#define HH (512*512)

__device__ __forceinline__ float leaky(float x) { return x > 0.f ? x : 0.2f * x; }

// ---------------- GEMM: C = act((beta*C + A@B + bias) * scale) ----------------
#define BM 64
#define BN 64
#define BK 16

template<int BETA, int LEAKY>
__global__ __launch_bounds__(256) void gemm_kernel(
    const float* __restrict__ A, const float* __restrict__ B,
    float* __restrict__ C, const float* __restrict__ bias,
    int M, int N, int K, float scale)
{
  __shared__ float As[BK][BM + 4];   // pad: write pattern c*68+r -> 2-way max (free)
  __shared__ float Bs[BK][BN];
  const int tid = threadIdx.x;
  const int bm = blockIdx.y * BM, bn = blockIdx.x * BN;
  const int tx = tid & 15, ty = tid >> 4;
  float acc[4][4] = {};
  for (int k0 = 0; k0 < K; k0 += BK) {
#pragma unroll
    for (int i = tid; i < BM * BK; i += 256) {
      int r = i >> 4, c = i & 15;
      int gr = bm + r, gc = k0 + c;
      As[c][r] = (gr < M && gc < K) ? A[(long)gr * K + gc] : 0.f;
    }
#pragma unroll
    for (int i = tid; i < BK * BN; i += 256) {
      int r = i >> 6, c = i & 63;
      int gr = k0 + r, gc = bn + c;
      Bs[r][c] = (gr < K && gc < N) ? B[(long)gr * N + gc] : 0.f;
    }
    __syncthreads();
#pragma unroll
    for (int k = 0; k < BK; k++) {
      float a[4], b[4];
#pragma unroll
      for (int i = 0; i < 4; i++) a[i] = As[k][ty * 4 + i];
#pragma unroll
      for (int j = 0; j < 4; j++) b[j] = Bs[k][tx * 4 + j];
#pragma unroll
      for (int i = 0; i < 4; i++)
#pragma unroll
        for (int j = 0; j < 4; j++) acc[i][j] += a[i] * b[j];
    }
    __syncthreads();
  }
#pragma unroll
  for (int i = 0; i < 4; i++) {
    int r = bm + ty * 4 + i;
    if (r >= M) continue;
#pragma unroll
    for (int j = 0; j < 4; j++) {
      int cc = bn + tx * 4 + j;
      if (cc >= N) continue;
      float v = acc[i][j];
      if (bias) v += bias[cc];
      if (BETA) v += C[(long)r * N + cc];
      v *= scale;
      if (LEAKY) v = leaky(v);
      C[(long)r * N + cc] = v;
    }
  }
}

// ---------------- CSR build (once per launch; graphs are layer-invariant) ----------------
__global__ void count_kernel(const int* __restrict__ dst, int* __restrict__ counts, int E) {
  int e = blockIdx.x * blockDim.x + threadIdx.x;
  if (e < E) atomicAdd(&counts[dst[e]], 1);
}

__global__ __launch_bounds__(1024) void scan_kernel(const int* __restrict__ counts,
                                                    int* __restrict__ offs, int n) {
  __shared__ int part[1024];
  int tid = threadIdx.x;
  int per = (n + 1023) / 1024;
  int s0 = tid * per, s1 = min(s0 + per, n);
  int s = 0;
  for (int i = s0; i < s1; i++) s += counts[i];
  part[tid] = s;
  __syncthreads();
  if (tid == 0) {
    int a = 0;
    for (int i = 0; i < 1024; i++) { int t = part[i]; part[i] = a; a += t; }
    offs[n] = a;
  }
  __syncthreads();
  int a = part[tid];
  for (int i = s0; i < s1; i++) { offs[i] = a; a += counts[i]; }
}

__global__ void fill_kernel(const int* __restrict__ src, const int* __restrict__ dst,
                            const int* __restrict__ ij, int* __restrict__ cursor,
                            int* __restrict__ ssrc, int* __restrict__ sij, int E) {
  int e = blockIdx.x * blockDim.x + threadIdx.x;
  if (e >= E) return;
  int d = dst[e];
  int p = atomicAdd(&cursor[d], 1);
  ssrc[p] = src[e];
  if (ij) sij[p] = ij[e];
}

// ---------------- weight pre-sums over relations ----------------
__global__ void wsum_kernel(const float* __restrict__ Wr, const float* __restrict__ Wg,
                            const float* __restrict__ b, float* __restrict__ WrS,
                            float* __restrict__ WgS, float* __restrict__ bS) {
  int i = blockIdx.x * blockDim.x + threadIdx.x;
  if (i < NLAYER * HH) {
    int l = i / HH, o = i % HH;
    long base = (long)l * 3 * HH + o;
    WrS[i] = Wr[base] + Wr[base + HH] + Wr[base + 2 * HH];
    WgS[i] = Wg[base] + Wg[base + HH] + Wg[base + 2 * HH];
  }
  if (i < NLAYER * H) {
    int l = i / H, o = i % H;
    bS[i] = b[l * 3 * H + o] + b[l * 3 * H + H + o] + b[l * 3 * H + 2 * H + o];
  }
}

// ---------------- pooling small kernels ----------------
// wv = scale * (Wk @ (S @ Wq)^T)
__global__ __launch_bounds__(512) void pool_qk_kernel(const float* __restrict__ S,
    const float* __restrict__ Wq, const float* __restrict__ Wk, float* __restrict__ wv) {
  __shared__ float s_sh[H], q_sh[H];
  int t = threadIdx.x;
  s_sh[t] = S[t];
  __syncthreads();
  float q = 0.f;
  for (int m = 0; m < H; m++) q += s_sh[m] * Wq[m * H + t];
  q_sh[t] = q;
  __syncthreads();
  int wave = t >> 6, lane = t & 63;
  const float scale = 0.04419417382415922f;  // 1/sqrt(512)
  for (int m = wave; m < H; m += 8) {
    float acc = 0.f;
    for (int j = lane; j < H; j += 64) acc += Wk[m * H + j] * q_sh[j];
#pragma unroll
    for (int o = 32; o > 0; o >>= 1) acc += __shfl_xor(acc, o);
    if (lane == 0) wv[m] = acc * scale;
  }
}

// s[i] = h1[i,:] . wv   (one wave per row)
__global__ __launch_bounds__(256) void scores_kernel(const float* __restrict__ h1,
    const float* __restrict__ wv, float* __restrict__ s, int n) {
  int row = blockIdx.x * 4 + (threadIdx.x >> 6);
  int lane = threadIdx.x & 63;
  if (row >= n) return;
  const float4* hp = (const float4*)(h1 + (long)row * H);
  const float4* wp = (const float4*)wv;
  float acc = 0.f;
#pragma unroll
  for (int i = 0; i < 2; i++) {
    float4 a = hp[lane + 64 * i];
    float4 w = wp[lane + 64 * i];
    acc += a.x * w.x + a.y * w.y + a.z * w.z + a.w * w.w;
  }
#pragma unroll
  for (int o = 32; o > 0; o >>= 1) acc += __shfl_xor(acc, o);
  if (lane == 0) s[row] = acc;
}

__global__ __launch_bounds__(256) void max_part_kernel(const float* __restrict__ s,
                                                       float* __restrict__ part, int n) {
  float m = -1e30f;
  for (int i = blockIdx.x * blockDim.x + threadIdx.x; i < n; i += gridDim.x * blockDim.x)
    m = fmaxf(m, s[i]);
  __shared__ float red[256];
  red[threadIdx.x] = m;
  __syncthreads();
  for (int o = 128; o > 0; o >>= 1) {
    if (threadIdx.x < o) red[threadIdx.x] = fmaxf(red[threadIdx.x], red[threadIdx.x + o]);
    __syncthreads();
  }
  if (threadIdx.x == 0) part[blockIdx.x] = red[0];
}

// reduce partial maxes, zero denom + pooled
__global__ __launch_bounds__(512) void max_fin_kernel(const float* __restrict__ part, int np,
    float* __restrict__ mout, float* __restrict__ denom, float* __restrict__ pooled) {
  if (threadIdx.x == 0) {
    float m = -1e30f;
    for (int i = 0; i < np; i++) m = fmaxf(m, part[i]);
    mout[0] = m;
    denom[0] = 0.f;
  }
  pooled[threadIdx.x] = 0.f;
}

__global__ __launch_bounds__(256) void expsum_kernel(float* __restrict__ s,
    const float* __restrict__ min_, float* __restrict__ denom, int n) {
  float m = min_[0];
  float local = 0.f;
  for (int i = blockIdx.x * blockDim.x + threadIdx.x; i < n; i += gridDim.x * blockDim.x) {
    float e = expf(s[i] - m);
    s[i] = e;
    local += e;
  }
  __shared__ float red[256];
  red[threadIdx.x] = local;
  __syncthreads();
  for (int o = 128; o > 0; o >>= 1) {
    if (threadIdx.x < o) red[threadIdx.x] += red[threadIdx.x + o];
    __syncthreads();
  }
  if (threadIdx.x == 0) atomicAdd(denom, red[0]);
}

// pooled[c] += sum_r e[r] * h1[r,c]
__global__ __launch_bounds__(256) void pool_weighted_kernel(const float* __restrict__ h1,
    const float* __restrict__ e, float* __restrict__ pooled, int n) {
  int c = threadIdx.x;
  int r0 = blockIdx.x * 128, r1 = min(r0 + 128, n);
  float a0 = 0.f, a1 = 0.f;
  for (int r = r0; r < r1; r++) {
    float w = e[r];
    a0 += w * h1[(long)r * H + c];
    a1 += w * h1[(long)r * H + c + 256];
  }
  atomicAdd(&pooled[c], a0);
  atomicAdd(&pooled[c + 256], a1);
}

// gvec = ((pooled/denom) @ Wv) @ L2W + L2b ; convbias = gvec @ WgS + bS
__global__ __launch_bounds__(512) void pool_fin_kernel(const float* __restrict__ pooled,
    const float* __restrict__ denom, const float* __restrict__ Wv,
    const float* __restrict__ L2W, const float* __restrict__ L2b,
    const float* __restrict__ WgS, const float* __restrict__ bS,
    float* __restrict__ convbias) {
  __shared__ float p[H], t1[H], g[H];
  int t = threadIdx.x;
  p[t] = pooled[t] / denom[0];
  __syncthreads();
  float a = 0.f;
  for (int m = 0; m < H; m++) a += p[m] * Wv[m * H + t];
  t1[t] = a;
  __syncthreads();
  a = L2b[t];
  for (int m = 0; m < H; m++) a += t1[m] * L2W[m * H + t];
  g[t] = a;
  __syncthreads();
  a = bS[t];
  for (int m = 0; m < H; m++) a += g[m] * WgS[m * H + t];
  convbias[t] = a;
}

// ---------------- segment-mean aggregations (CSR, no atomics) ----------------
__global__ __launch_bounds__(128) void agg_win_kernel(const float* __restrict__ hw,
    const float* __restrict__ he, const int* __restrict__ offs,
    const int* __restrict__ ssrc, const int* __restrict__ sij, float* __restrict__ agg) {
  const int node = blockIdx.x;
  const int c = threadIdx.x << 2;
  const int beg = offs[node], end = offs[node + 1];
  float4 acc = make_float4(0.f, 0.f, 0.f, 0.f);
  for (int e = beg; e < end; e++) {
    const int s = ssrc[e], j = sij[e];
    const float4 a = *(const float4*)(hw + (long)s * H + c);
    const float4 b = *(const float4*)(he + (long)j * H + c);
    acc.x += a.x + b.x; acc.y += a.y + b.y; acc.z += a.z + b.z; acc.w += a.w + b.w;
  }
  const float inv = 1.f / (float)max(end - beg, 1);
  float4 o = make_float4(acc.x * inv, acc.y * inv, acc.z * inv, acc.w * inv);
  *(float4*)(agg + (long)node * H + c) = o;
}

__global__ __launch_bounds__(128) void agg_edge_kernel(const float* __restrict__ he,
    const int* __restrict__ offs, const int* __restrict__ ssrc, float* __restrict__ agg) {
  const int node = blockIdx.x;
  const int c = threadIdx.x << 2;
  const int beg = offs[node], end = offs[node + 1];
  float4 acc = make_float4(0.f, 0.f, 0.f, 0.f);
  for (int e = beg; e < end; e++) {
    const int s = ssrc[e];
    const float4 a = *(const float4*)(he + (long)s * H + c);
    acc.x += a.x; acc.y += a.y; acc.z += a.z; acc.w += a.w;
  }
  const float inv = 1.f / (float)max(end - beg, 1);
  float4 o = make_float4(acc.x * inv, acc.y * inv, acc.z * inv, acc.w * inv);
  *(float4*)(agg + (long)node * H + c) = o;
}

// ---------------- host launch ----------------
extern "C" void kernel_launch(void* const* d_in, const int* in_sizes, int n_in,
                              void* d_out, int out_size, void* d_ws, size_t ws_size,
                              hipStream_t stream) {
  const float* x_win   = (const float*)d_in[0];
  const float* x_edge  = (const float*)d_in[1];
  const float* Wpre_w  = (const float*)d_in[2];
  const float* Wpost_w = (const float*)d_in[3];
  const float* Wpre_e  = (const float*)d_in[4];
  const float* Wpost_e = (const float*)d_in[5];
  const float* convWl  = (const float*)d_in[6];
  const float* convWr  = (const float*)d_in[7];
  const float* convWg  = (const float*)d_in[8];
  const float* convB   = (const float*)d_in[9];
  const float* eWl     = (const float*)d_in[10];
  const float* eWr     = (const float*)d_in[11];
  const float* eB      = (const float*)d_in[12];
  const float* p1W     = (const float*)d_in[13];
  const float* p1b     = (const float*)d_in[14];
  const float* pS      = (const float*)d_in[15];
  const float* pWq     = (const float*)d_in[16];
  const float* pWk     = (const float*)d_in[17];
  const float* pWv     = (const float*)d_in[18];
  const float* p2W     = (const float*)d_in[19];
  const float* p2b     = (const float*)d_in[20];
  const float* linW    = (const float*)d_in[21];
  const float* linb    = (const float*)d_in[22];
  const int* ei_near   = (const int*)d_in[23];
  const int* ei_close  = (const int*)d_in[24];
  const int* ei_sim    = (const int*)d_in[25];
  const int* ij_near   = (const int*)d_in[26];
  const int* ij_close  = (const int*)d_in[27];
  const int* ij_sim    = (const int*)d_in[28];
  const int* ee_idx    = (const int*)d_in[29];
  float* out = (float*)d_out;

  char* ws = (char*)d_ws;
  size_t off = 0;
  auto alloc = [&](size_t bytes) -> void* {
    off = (off + 255) & ~(size_t)255;
    void* p = ws + off;
    off += bytes;
    return p;
  };
  float* hw    = (float*)alloc((size_t)NW * H * 4);
  float* hwacc = (float*)alloc((size_t)NW * H * 4);
  float* he    = (float*)alloc((size_t)NE * H * 4);
  float* heacc = (float*)alloc((size_t)NE * H * 4);
  float* tmp   = (float*)alloc((size_t)NE * H * 4);   // pre-transform temp / h1 / agg_e (sequenced)
  float* aggw  = (float*)alloc((size_t)NW * H * 4);
  float* WrS   = (float*)alloc((size_t)NLAYER * HH * 4);
  float* WgS   = (float*)alloc((size_t)NLAYER * HH * 4);
  float* bS    = (float*)alloc((size_t)NLAYER * H * 4);
  float* convbias = (float*)alloc(H * 4);
  float* wv    = (float*)alloc(H * 4);
  float* pooled= (float*)alloc(H * 4);
  float* scores= (float*)alloc(NW * 4);
  float* parts = (float*)alloc(64 * 4);
  float* scal  = (float*)alloc(8 * 4);   // [0]=max, [1]=denom
  int* counts  = (int*)alloc(90000 * 4);
  int* offs    = (int*)alloc(90004 * 4);
  int* cursor  = (int*)alloc(90000 * 4);
  int* ssrc    = (int*)alloc(800000 * 4);
  int* sij     = (int*)alloc(600000 * 4);

  float* maxv = scal, *denom = scal + 1;

  auto gemm = [&](int beta, int lk, const float* A, const float* B, float* C,
                  const float* bias, int M, int N, int K, float scale) {
    dim3 g((N + BN - 1) / BN, (M + BM - 1) / BM);
    if (!beta && !lk) hipLaunchKernelGGL((gemm_kernel<0,0>), g, dim3(256), 0, stream, A, B, C, bias, M, N, K, scale);
    else if (!beta)   hipLaunchKernelGGL((gemm_kernel<0,1>), g, dim3(256), 0, stream, A, B, C, bias, M, N, K, scale);
    else if (!lk)     hipLaunchKernelGGL((gemm_kernel<1,0>), g, dim3(256), 0, stream, A, B, C, bias, M, N, K, scale);
    else              hipLaunchKernelGGL((gemm_kernel<1,1>), g, dim3(256), 0, stream, A, B, C, bias, M, N, K, scale);
  };

  // ---- CSR build (graphs fixed across layers) ----
  hipMemsetAsync(counts, 0, 90000 * 4, stream);
  dim3 eg((ER + 255) / 256), bg(256);
  count_kernel<<<eg, bg, 0, stream>>>(ei_near + ER, counts,         ER);
  count_kernel<<<eg, bg, 0, stream>>>(ei_close + ER, counts + 20000, ER);
  count_kernel<<<eg, bg, 0, stream>>>(ei_sim + ER, counts + 40000,  ER);
  count_kernel<<<eg, bg, 0, stream>>>(ee_idx + EE, counts + 60000,  EE);
  scan_kernel<<<1, 1024, 0, stream>>>(counts,         offs,         NW);
  scan_kernel<<<1, 1024, 0, stream>>>(counts + 20000, offs + 20001, NW);
  scan_kernel<<<1, 1024, 0, stream>>>(counts + 40000, offs + 40002, NW);
  scan_kernel<<<1, 1024, 0, stream>>>(counts + 60000, offs + 60003, NE);
  hipMemcpyAsync(cursor,          offs,          20000 * 4, hipMemcpyDeviceToDevice, stream);
  hipMemcpyAsync(cursor + 20000,  offs + 20001,  20000 * 4, hipMemcpyDeviceToDevice, stream);
  hipMemcpyAsync(cursor + 40000,  offs + 40002,  20000 * 4, hipMemcpyDeviceToDevice, stream);
  hipMemcpyAsync(cursor + 60000,  offs + 60003,  30000 * 4, hipMemcpyDeviceToDevice, stream);
  fill_kernel<<<eg, bg, 0, stream>>>(ei_near,  ei_near + ER,  ij_near,  cursor,         ssrc,          sij,          ER);
  fill_kernel<<<eg, bg, 0, stream>>>(ei_close, ei_close + ER, ij_close, cursor + 20000, ssrc + ER,     sij + ER,     ER);
  fill_kernel<<<eg, bg, 0, stream>>>(ei_sim,   ei_sim + ER,   ij_sim,   cursor + 40000, ssrc + 2 * ER, sij + 2 * ER, ER);
  fill_kernel<<<eg, bg, 0, stream>>>(ee_idx,   ee_idx + EE,   nullptr,  cursor + 60000, ssrc + 3 * ER, nullptr,      EE);

  // ---- relation-summed weights ----
  wsum_kernel<<<(NLAYER * HH + 255) / 256, 256, 0, stream>>>(convWr, convWg, convB, WrS, WgS, bS);

  // ---- pre-transforms ----
  gemm(0, 1, x_win,  Wpre_w,  tmp, nullptr, NW, H, MDIM, 1.f);
  gemm(0, 1, tmp,    Wpost_w, hw,  nullptr, NW, H, H,    1.f);
  gemm(0, 1, x_edge, Wpre_e,  tmp, nullptr, NE, H, ECH,  1.f);
  gemm(0, 1, tmp,    Wpost_e, he,  nullptr, NE, H, H,    1.f);

  const int* offs_ee = offs + 60003;
  for (int l = 0; l < NLAYER; l++) {
    // pooling: h1 -> scores -> softmax -> pooled -> gvec -> convbias
    gemm(0, 0, hw, p1W + (size_t)l * HH, tmp, p1b + l * H, NW, H, H, 1.f);
    pool_qk_kernel<<<1, 512, 0, stream>>>(pS + l * H, pWq + (size_t)l * HH, pWk + (size_t)l * HH, wv);
    scores_kernel<<<NW / 4, 256, 0, stream>>>(tmp, wv, scores, NW);
    max_part_kernel<<<40, 256, 0, stream>>>(scores, parts, NW);
    max_fin_kernel<<<1, 512, 0, stream>>>(parts, 40, maxv, denom, pooled);
    expsum_kernel<<<40, 256, 0, stream>>>(scores, maxv, denom, NW);
    pool_weighted_kernel<<<(NW + 127) / 128, 256, 0, stream>>>(tmp, scores, pooled, NW);
    pool_fin_kernel<<<1, 512, 0, stream>>>(pooled, denom, pWv + (size_t)l * HH,
        p2W + (size_t)l * HH, p2b + l * H, WgS + (size_t)l * HH, bS + l * H, convbias);

    // window conv: 3 relation aggregations + GEMM accumulate
    for (int r = 0; r < 3; r++) {
      agg_win_kernel<<<NW, 128, 0, stream>>>(hw, he, offs + r * 20001, ssrc + (size_t)r * ER,
                                             sij + (size_t)r * ER, aggw);
      if (r == 0) gemm(0, 0, aggw, convWl + ((size_t)l * 3 + r) * HH, hwacc, convbias, NW, H, H, 1.f);
      else        gemm(1, 0, aggw, convWl + ((size_t)l * 3 + r) * HH, hwacc, nullptr,  NW, H, H, 1.f);
    }
    gemm(1, 1, hw, WrS + (size_t)l * HH, hwacc, nullptr, NW, H, H, 1.f / 3.f);  // /3 + leaky

    // edge conv (uses old h_e; tmp reused as agg_e — h1 is dead by now)
    agg_edge_kernel<<<NE, 128, 0, stream>>>(he, offs_ee, ssrc + 3 * (size_t)ER, tmp);
    gemm(0, 0, tmp, eWl + (size_t)l * HH, heacc, eB + l * H, NE, H, H, 1.f);
    gemm(1, 1, he,  eWr + (size_t)l * HH, heacc, nullptr,    NE, H, H, 1.f);

    { float* t = hw; hw = hwacc; hwacc = t; }
    { float* t = he; he = heacc; heacc = t; }
  }

  // final linear
  gemm(0, 0, hw, linW, out, linb, NW, OUT_DIM, H, 1.f);
}

// Round 2
// 6869.160 us; speedup vs baseline: 2.0010x; 2.0010x over previous
//
#include <hip/hip_runtime.h>

#define NW 20000
#define NE 30000
#define ER 200000
#define EE 200000
#define H 512
#define MDIM 512
#define ECH 4101
#define OUT_DIM 250
#define NLAYER 4
#define HH (512*512)
#define NWP 20096   // ceil(NW/128)*128
#define NEP 30080   // ceil(NE/128)*128
#define KECHP 4128  // ceil(ECH/32)*32

typedef unsigned short u16;
typedef unsigned int u32;
typedef __attribute__((ext_vector_type(8))) short bf16x8;
typedef __attribute__((ext_vector_type(4))) float f32x4;

__device__ __forceinline__ float leaky(float x) { return x > 0.f ? x : 0.2f * x; }

__device__ __forceinline__ u16 f2bf(float x) {
  u32 u = __float_as_uint(x);
  u += 0x7FFF + ((u >> 16) & 1);
  return (u16)(u >> 16);
}
__device__ __forceinline__ float bf2f(u16 h) { return __uint_as_float((u32)h << 16); }
__device__ __forceinline__ void splitbf(float v, u16& h, u16& l) {
  h = f2bf(v);
  l = f2bf(v - bf2f(h));
}

__device__ __forceinline__ void gload16(const void* g, void* l) {
  __builtin_amdgcn_global_load_lds(
      (const __attribute__((address_space(1))) unsigned int*)g,
      (__attribute__((address_space(3))) unsigned int*)l, 16, 0, 0);
}

// ================= split-bf16 MFMA GEMM =================
// C[M,N] = act(scale * (beta*C + A@B + bias)); A given as hi/lo bf16 [Mpad][KaA],
// B given TRANSPOSED hi/lo bf16 [Npad][KaB] (element (k,n) at Bt[n*KaB + kBoff + k]).
// MODE: 0 = write fp32 C; 1 = write hi/lo O only; 2 = both. O stride = N.
template<int BETA, int LEAKY, int MODE>
__global__ __launch_bounds__(256) void mgemm(
    const u16* __restrict__ Ah, const u16* __restrict__ Al, int KaA,
    const u16* __restrict__ Bh, const u16* __restrict__ Bl, int KaB, int kBoff,
    float* __restrict__ C, const float* __restrict__ bias,
    u16* __restrict__ Oh, u16* __restrict__ Ol,
    int M, int N, float scale)
{
  __shared__ __align__(16) u16 sAh[4096], sAl[4096], sBh[4096], sBl[4096];
  const int t = threadIdx.x;
  const int bm = blockIdx.y * 128, bn = blockIdx.x * 128;
  const int lane = t & 63, w = t >> 6;
  const int wr = (w >> 1) * 64, wc = (w & 1) * 64;
  const int lm = lane & 15, lk = (lane >> 4) * 8;

  const u16* gAh = Ah + (size_t)(bm + (t >> 2)) * KaA + ((t & 3) * 8);
  const u16* gAl = Al + (size_t)(bm + (t >> 2)) * KaA + ((t & 3) * 8);
  const u16* gBh = Bh + (size_t)(bn + (t >> 2)) * KaB + kBoff + ((t & 3) * 8);
  const u16* gBl = Bl + (size_t)(bn + (t >> 2)) * KaB + kBoff + ((t & 3) * 8);
  const size_t a64 = (size_t)64 * KaA, b64 = (size_t)64 * KaB;

  f32x4 acc[4][4] = {};
  for (int k0 = 0; k0 < KaA; k0 += 32) {
    gload16(gAh + k0,       sAh + t * 8);
    gload16(gAh + a64 + k0, sAh + 2048 + t * 8);
    gload16(gAl + k0,       sAl + t * 8);
    gload16(gAl + a64 + k0, sAl + 2048 + t * 8);
    gload16(gBh + k0,       sBh + t * 8);
    gload16(gBh + b64 + k0, sBh + 2048 + t * 8);
    gload16(gBl + k0,       sBl + t * 8);
    gload16(gBl + b64 + k0, sBl + 2048 + t * 8);
    __syncthreads();
    bf16x8 ah[4], al[4], bh[4], bl[4];
#pragma unroll
    for (int f = 0; f < 4; f++) {
      ah[f] = *(const bf16x8*)(sAh + (wr + f * 16 + lm) * 32 + lk);
      al[f] = *(const bf16x8*)(sAl + (wr + f * 16 + lm) * 32 + lk);
      bh[f] = *(const bf16x8*)(sBh + (wc + f * 16 + lm) * 32 + lk);
      bl[f] = *(const bf16x8*)(sBl + (wc + f * 16 + lm) * 32 + lk);
    }
#pragma unroll
    for (int i = 0; i < 4; i++)
#pragma unroll
      for (int j = 0; j < 4; j++) {
        acc[i][j] = __builtin_amdgcn_mfma_f32_16x16x32_bf16(ah[i], bh[j], acc[i][j], 0, 0, 0);
        acc[i][j] = __builtin_amdgcn_mfma_f32_16x16x32_bf16(ah[i], bl[j], acc[i][j], 0, 0, 0);
        acc[i][j] = __builtin_amdgcn_mfma_f32_16x16x32_bf16(al[i], bh[j], acc[i][j], 0, 0, 0);
      }
    __syncthreads();
  }
#pragma unroll
  for (int i = 0; i < 4; i++) {
    const int rb = bm + wr + i * 16 + (lane >> 4) * 4;
#pragma unroll
    for (int j = 0; j < 4; j++) {
      const int col = bn + wc + j * 16 + lm;
      if (col >= N) continue;
#pragma unroll
      for (int r = 0; r < 4; r++) {
        const int row = rb + r;
        if (row >= M) continue;
        float v = acc[i][j][r];
        if (bias) v += bias[col];
        if (BETA) v += C[(size_t)row * N + col];
        v *= scale;
        if (LEAKY) v = leaky(v);
        if (MODE != 1) C[(size_t)row * N + col] = v;
        if (MODE >= 1) {
          u16 h, l; splitbf(v, h, l);
          Oh[(size_t)row * N + col] = h;
          Ol[(size_t)row * N + col] = l;
        }
      }
    }
  }
}

// fp32 [M rows, rowStride] (cols kSrcOff..kSrcOff+kLen) -> hi/lo bf16 [Mpad][Kpad], zero-padded
__global__ __launch_bounds__(256) void convert_rows(
    const float* __restrict__ X, u16* __restrict__ Oh, u16* __restrict__ Ol,
    int M, int rowStride, int kSrcOff, int kLen, int Kpad, int Mpad)
{
  const int cpr = Kpad >> 3;
  int idx = blockIdx.x * 256 + threadIdx.x;
  int row = idx / cpr;
  if (row >= Mpad) return;
  int kc = (idx - row * cpr) << 3;
  u16 h[8], l[8];
#pragma unroll
  for (int j = 0; j < 8; j++) {
    int k = kc + j;
    float v = (row < M && k < kLen) ? X[(size_t)row * rowStride + kSrcOff + k] : 0.f;
    splitbf(v, h[j], l[j]);
  }
  u32 wh[4], wl[4];
#pragma unroll
  for (int j = 0; j < 4; j++) {
    wh[j] = (u32)h[2 * j] | ((u32)h[2 * j + 1] << 16);
    wl[j] = (u32)l[2 * j] | ((u32)l[2 * j + 1] << 16);
  }
  *(uint4*)(Oh + (size_t)row * Kpad + kc) = make_uint4(wh[0], wh[1], wh[2], wh[3]);
  *(uint4*)(Ol + (size_t)row * Kpad + kc) = make_uint4(wl[0], wl[1], wl[2], wl[3]);
}

// fp32 W [b][K][N] -> transposed hi/lo bf16 [b][Npad][Kpad], zero-padded
__global__ void convert_w(const float* __restrict__ W, u16* __restrict__ Oh,
                          u16* __restrict__ Ol, int K, int N, int Kpad, int Npad)
{
  __shared__ float tile[32][33];
  const int b = blockIdx.z;
  const float* Wb = W + (size_t)b * K * N;
  const size_t ob = (size_t)b * Npad * Kpad;
  const int n0 = blockIdx.x * 32, k0 = blockIdx.y * 32;
#pragma unroll
  for (int i = 0; i < 4; i++) {
    int k = k0 + threadIdx.y + i * 8, n = n0 + threadIdx.x;
    tile[threadIdx.y + i * 8][threadIdx.x] = (k < K && n < N) ? Wb[(size_t)k * N + n] : 0.f;
  }
  __syncthreads();
#pragma unroll
  for (int i = 0; i < 4; i++) {
    int n = n0 + threadIdx.y + i * 8, kk = k0 + threadIdx.x;
    float v = tile[threadIdx.x][threadIdx.y + i * 8];
    u16 h, l; splitbf(v, h, l);
    Oh[ob + (size_t)n * Kpad + kk] = h;
    Ol[ob + (size_t)n * Kpad + kk] = l;
  }
}

// ---------------- CSR build ----------------
__global__ void count_kernel(const int* __restrict__ dst, int* __restrict__ counts, int E) {
  int e = blockIdx.x * blockDim.x + threadIdx.x;
  if (e < E) atomicAdd(&counts[dst[e]], 1);
}

__global__ __launch_bounds__(1024) void scan_kernel(const int* __restrict__ counts,
                                                    int* __restrict__ offs, int n) {
  __shared__ int part[1024];
  int tid = threadIdx.x;
  int per = (n + 1023) / 1024;
  int s0 = tid * per, s1 = min(s0 + per, n);
  int s = 0;
  for (int i = s0; i < s1; i++) s += counts[i];
  part[tid] = s;
  __syncthreads();
  if (tid == 0) {
    int a = 0;
    for (int i = 0; i < 1024; i++) { int t = part[i]; part[i] = a; a += t; }
    offs[n] = a;
  }
  __syncthreads();
  int a = part[tid];
  for (int i = s0; i < s1; i++) { offs[i] = a; a += counts[i]; }
}

__global__ void fill_kernel(const int* __restrict__ src, const int* __restrict__ dst,
                            const int* __restrict__ ij, int* __restrict__ cursor,
                            int* __restrict__ ssrc, int* __restrict__ sij, int E) {
  int e = blockIdx.x * blockDim.x + threadIdx.x;
  if (e >= E) return;
  int d = dst[e];
  int p = atomicAdd(&cursor[d], 1);
  ssrc[p] = src[e];
  if (ij) sij[p] = ij[e];
}

// ---------------- weight pre-sums over relations ----------------
__global__ void wsum_kernel(const float* __restrict__ Wr, const float* __restrict__ Wg,
                            const float* __restrict__ b, float* __restrict__ WrS,
                            float* __restrict__ WgS, float* __restrict__ bS) {
  int i = blockIdx.x * blockDim.x + threadIdx.x;
  if (i < NLAYER * HH) {
    int l = i / HH, o = i % HH;
    long base = (long)l * 3 * HH + o;
    WrS[i] = Wr[base] + Wr[base + HH] + Wr[base + 2 * HH];
    WgS[i] = Wg[base] + Wg[base + HH] + Wg[base + 2 * HH];
  }
  if (i < NLAYER * H) {
    int l = i / H, o = i % H;
    bS[i] = b[l * 3 * H + o] + b[l * 3 * H + H + o] + b[l * 3 * H + 2 * H + o];
  }
}

// ---------------- pooling small kernels ----------------
__global__ __launch_bounds__(512) void pool_qk_kernel(const float* __restrict__ S,
    const float* __restrict__ Wq, const float* __restrict__ Wk, float* __restrict__ wv) {
  __shared__ float s_sh[H], q_sh[H];
  int t = threadIdx.x;
  s_sh[t] = S[t];
  __syncthreads();
  float q = 0.f;
  for (int m = 0; m < H; m++) q += s_sh[m] * Wq[m * H + t];
  q_sh[t] = q;
  __syncthreads();
  int wave = t >> 6, lane = t & 63;
  const float scale = 0.04419417382415922f;  // 1/sqrt(512)
  for (int m = wave; m < H; m += 8) {
    float acc = 0.f;
    for (int j = lane; j < H; j += 64) acc += Wk[m * H + j] * q_sh[j];
#pragma unroll
    for (int o = 32; o > 0; o >>= 1) acc += __shfl_xor(acc, o);
    if (lane == 0) wv[m] = acc * scale;
  }
}

__global__ __launch_bounds__(256) void scores_kernel(const float* __restrict__ h1,
    const float* __restrict__ wv, float* __restrict__ s, int n) {
  int row = blockIdx.x * 4 + (threadIdx.x >> 6);
  int lane = threadIdx.x & 63;
  if (row >= n) return;
  const float4* hp = (const float4*)(h1 + (long)row * H);
  const float4* wp = (const float4*)wv;
  float acc = 0.f;
#pragma unroll
  for (int i = 0; i < 2; i++) {
    float4 a = hp[lane + 64 * i];
    float4 w = wp[lane + 64 * i];
    acc += a.x * w.x + a.y * w.y + a.z * w.z + a.w * w.w;
  }
#pragma unroll
  for (int o = 32; o > 0; o >>= 1) acc += __shfl_xor(acc, o);
  if (lane == 0) s[row] = acc;
}

__global__ __launch_bounds__(256) void max_part_kernel(const float* __restrict__ s,
                                                       float* __restrict__ part, int n) {
  float m = -1e30f;
  for (int i = blockIdx.x * blockDim.x + threadIdx.x; i < n; i += gridDim.x * blockDim.x)
    m = fmaxf(m, s[i]);
  __shared__ float red[256];
  red[threadIdx.x] = m;
  __syncthreads();
  for (int o = 128; o > 0; o >>= 1) {
    if (threadIdx.x < o) red[threadIdx.x] = fmaxf(red[threadIdx.x], red[threadIdx.x + o]);
    __syncthreads();
  }
  if (threadIdx.x == 0) part[blockIdx.x] = red[0];
}

__global__ __launch_bounds__(512) void max_fin_kernel(const float* __restrict__ part, int np,
    float* __restrict__ mout, float* __restrict__ denom, float* __restrict__ pooled) {
  if (threadIdx.x == 0) {
    float m = -1e30f;
    for (int i = 0; i < np; i++) m = fmaxf(m, part[i]);
    mout[0] = m;
    denom[0] = 0.f;
  }
  pooled[threadIdx.x] = 0.f;
}

__global__ __launch_bounds__(256) void expsum_kernel(float* __restrict__ s,
    const float* __restrict__ min_, float* __restrict__ denom, int n) {
  float m = min_[0];
  float local = 0.f;
  for (int i = blockIdx.x * blockDim.x + threadIdx.x; i < n; i += gridDim.x * blockDim.x) {
    float e = expf(s[i] - m);
    s[i] = e;
    local += e;
  }
  __shared__ float red[256];
  red[threadIdx.x] = local;
  __syncthreads();
  for (int o = 128; o > 0; o >>= 1) {
    if (threadIdx.x < o) red[threadIdx.x] += red[threadIdx.x + o];
    __syncthreads();
  }
  if (threadIdx.x == 0) atomicAdd(denom, red[0]);
}

__global__ __launch_bounds__(256) void pool_weighted_kernel(const float* __restrict__ h1,
    const float* __restrict__ e, float* __restrict__ pooled, int n) {
  int c = threadIdx.x;
  int r0 = blockIdx.x * 128, r1 = min(r0 + 128, n);
  float a0 = 0.f, a1 = 0.f;
  for (int r = r0; r < r1; r++) {
    float w = e[r];
    a0 += w * h1[(long)r * H + c];
    a1 += w * h1[(long)r * H + c + 256];
  }
  atomicAdd(&pooled[c], a0);
  atomicAdd(&pooled[c + 256], a1);
}

__global__ __launch_bounds__(512) void pool_fin_kernel(const float* __restrict__ pooled,
    const float* __restrict__ denom, const float* __restrict__ Wv,
    const float* __restrict__ L2W, const float* __restrict__ L2b,
    const float* __restrict__ WgS, const float* __restrict__ bS,
    float* __restrict__ convbias) {
  __shared__ float p[H], t1[H], g[H];
  int t = threadIdx.x;
  p[t] = pooled[t] / denom[0];
  __syncthreads();
  float a = 0.f;
  for (int m = 0; m < H; m++) a += p[m] * Wv[m * H + t];
  t1[t] = a;
  __syncthreads();
  a = L2b[t];
  for (int m = 0; m < H; m++) a += t1[m] * L2W[m * H + t];
  g[t] = a;
  __syncthreads();
  a = bS[t];
  for (int m = 0; m < H; m++) a += g[m] * WgS[m * H + t];
  convbias[t] = a;
}

// ---------------- segment-mean aggregations -> hi/lo bf16 ----------------
__global__ __launch_bounds__(128) void agg_win_bf(const float* __restrict__ hw,
    const float* __restrict__ he, const int* __restrict__ offs,
    const int* __restrict__ ssrc, const int* __restrict__ sij,
    u16* __restrict__ Oh, u16* __restrict__ Ol, int n) {
  const int node = blockIdx.x;
  const int c = threadIdx.x << 2;
  float4 acc = make_float4(0.f, 0.f, 0.f, 0.f);
  if (node < n) {
    const int beg = offs[node], end = offs[node + 1];
    for (int e = beg; e < end; e++) {
      const int s = ssrc[e], j = sij[e];
      const float4 a = *(const float4*)(hw + (long)s * H + c);
      const float4 b = *(const float4*)(he + (long)j * H + c);
      acc.x += a.x + b.x; acc.y += a.y + b.y; acc.z += a.z + b.z; acc.w += a.w + b.w;
    }
    const float inv = 1.f / (float)max(end - beg, 1);
    acc.x *= inv; acc.y *= inv; acc.z *= inv; acc.w *= inv;
  }
  ushort4 h4, l4;
  splitbf(acc.x, h4.x, l4.x); splitbf(acc.y, h4.y, l4.y);
  splitbf(acc.z, h4.z, l4.z); splitbf(acc.w, h4.w, l4.w);
  *(ushort4*)(Oh + (size_t)node * H + c) = h4;
  *(ushort4*)(Ol + (size_t)node * H + c) = l4;
}

__global__ __launch_bounds__(128) void agg_edge_bf(const float* __restrict__ he,
    const int* __restrict__ offs, const int* __restrict__ ssrc,
    u16* __restrict__ Oh, u16* __restrict__ Ol, int n) {
  const int node = blockIdx.x;
  const int c = threadIdx.x << 2;
  float4 acc = make_float4(0.f, 0.f, 0.f, 0.f);
  if (node < n) {
    const int beg = offs[node], end = offs[node + 1];
    for (int e = beg; e < end; e++) {
      const int s = ssrc[e];
      const float4 a = *(const float4*)(he + (long)s * H + c);
      acc.x += a.x; acc.y += a.y; acc.z += a.z; acc.w += a.w;
    }
    const float inv = 1.f / (float)max(end - beg, 1);
    acc.x *= inv; acc.y *= inv; acc.z *= inv; acc.w *= inv;
  }
  ushort4 h4, l4;
  splitbf(acc.x, h4.x, l4.x); splitbf(acc.y, h4.y, l4.y);
  splitbf(acc.z, h4.z, l4.z); splitbf(acc.w, h4.w, l4.w);
  *(ushort4*)(Oh + (size_t)node * H + c) = h4;
  *(ushort4*)(Ol + (size_t)node * H + c) = l4;
}

// ---------------- fallback fp32 GEMM + aggs (round-1 path) ----------------
#define BM 64
#define BN 64
#define BK 16
template<int BETA, int LEAKY>
__global__ __launch_bounds__(256) void gemm_kernel(
    const float* __restrict__ A, const float* __restrict__ B,
    float* __restrict__ C, const float* __restrict__ bias,
    int M, int N, int K, float scale)
{
  __shared__ float As[BK][BM + 4];
  __shared__ float Bs[BK][BN];
  const int tid = threadIdx.x;
  const int bm = blockIdx.y * BM, bn = blockIdx.x * BN;
  const int tx = tid & 15, ty = tid >> 4;
  float acc[4][4] = {};
  for (int k0 = 0; k0 < K; k0 += BK) {
#pragma unroll
    for (int i = tid; i < BM * BK; i += 256) {
      int r = i >> 4, c = i & 15;
      int gr = bm + r, gc = k0 + c;
      As[c][r] = (gr < M && gc < K) ? A[(long)gr * K + gc] : 0.f;
    }
#pragma unroll
    for (int i = tid; i < BK * BN; i += 256) {
      int r = i >> 6, c = i & 63;
      int gr = k0 + r, gc = bn + c;
      Bs[r][c] = (gr < K && gc < N) ? B[(long)gr * N + gc] : 0.f;
    }
    __syncthreads();
#pragma unroll
    for (int k = 0; k < BK; k++) {
      float a[4], b[4];
#pragma unroll
      for (int i = 0; i < 4; i++) a[i] = As[k][ty * 4 + i];
#pragma unroll
      for (int j = 0; j < 4; j++) b[j] = Bs[k][tx * 4 + j];
#pragma unroll
      for (int i = 0; i < 4; i++)
#pragma unroll
        for (int j = 0; j < 4; j++) acc[i][j] += a[i] * b[j];
    }
    __syncthreads();
  }
#pragma unroll
  for (int i = 0; i < 4; i++) {
    int r = bm + ty * 4 + i;
    if (r >= M) continue;
#pragma unroll
    for (int j = 0; j < 4; j++) {
      int cc = bn + tx * 4 + j;
      if (cc >= N) continue;
      float v = acc[i][j];
      if (bias) v += bias[cc];
      if (BETA) v += C[(long)r * N + cc];
      v *= scale;
      if (LEAKY) v = leaky(v);
      C[(long)r * N + cc] = v;
    }
  }
}

__global__ __launch_bounds__(128) void agg_win_f32(const float* __restrict__ hw,
    const float* __restrict__ he, const int* __restrict__ offs,
    const int* __restrict__ ssrc, const int* __restrict__ sij, float* __restrict__ agg) {
  const int node = blockIdx.x;
  const int c = threadIdx.x << 2;
  const int beg = offs[node], end = offs[node + 1];
  float4 acc = make_float4(0.f, 0.f, 0.f, 0.f);
  for (int e = beg; e < end; e++) {
    const int s = ssrc[e], j = sij[e];
    const float4 a = *(const float4*)(hw + (long)s * H + c);
    const float4 b = *(const float4*)(he + (long)j * H + c);
    acc.x += a.x + b.x; acc.y += a.y + b.y; acc.z += a.z + b.z; acc.w += a.w + b.w;
  }
  const float inv = 1.f / (float)max(end - beg, 1);
  *(float4*)(agg + (long)node * H + c) =
      make_float4(acc.x * inv, acc.y * inv, acc.z * inv, acc.w * inv);
}

__global__ __launch_bounds__(128) void agg_edge_f32(const float* __restrict__ he,
    const int* __restrict__ offs, const int* __restrict__ ssrc, float* __restrict__ agg) {
  const int node = blockIdx.x;
  const int c = threadIdx.x << 2;
  const int beg = offs[node], end = offs[node + 1];
  float4 acc = make_float4(0.f, 0.f, 0.f, 0.f);
  for (int e = beg; e < end; e++) {
    const int s = ssrc[e];
    const float4 a = *(const float4*)(he + (long)s * H + c);
    acc.x += a.x; acc.y += a.y; acc.z += a.z; acc.w += a.w;
  }
  const float inv = 1.f / (float)max(end - beg, 1);
  *(float4*)(agg + (long)node * H + c) =
      make_float4(acc.x * inv, acc.y * inv, acc.z * inv, acc.w * inv);
}

// ---------------- host launch ----------------
extern "C" void kernel_launch(void* const* d_in, const int* in_sizes, int n_in,
                              void* d_out, int out_size, void* d_ws, size_t ws_size,
                              hipStream_t stream) {
  const float* x_win   = (const float*)d_in[0];
  const float* x_edge  = (const float*)d_in[1];
  const float* Wpre_w  = (const float*)d_in[2];
  const float* Wpost_w = (const float*)d_in[3];
  const float* Wpre_e  = (const float*)d_in[4];
  const float* Wpost_e = (const float*)d_in[5];
  const float* convWl  = (const float*)d_in[6];
  const float* convWr  = (const float*)d_in[7];
  const float* convWg  = (const float*)d_in[8];
  const float* convB   = (const float*)d_in[9];
  const float* eWl     = (const float*)d_in[10];
  const float* eWr     = (const float*)d_in[11];
  const float* eB      = (const float*)d_in[12];
  const float* p1W     = (const float*)d_in[13];
  const float* p1b     = (const float*)d_in[14];
  const float* pS      = (const float*)d_in[15];
  const float* pWq     = (const float*)d_in[16];
  const float* pWk     = (const float*)d_in[17];
  const float* pWv     = (const float*)d_in[18];
  const float* p2W     = (const float*)d_in[19];
  const float* p2b     = (const float*)d_in[20];
  const float* linW    = (const float*)d_in[21];
  const float* linb    = (const float*)d_in[22];
  const int* ei_near   = (const int*)d_in[23];
  const int* ei_close  = (const int*)d_in[24];
  const int* ei_sim    = (const int*)d_in[25];
  const int* ij_near   = (const int*)d_in[26];
  const int* ij_close  = (const int*)d_in[27];
  const int* ij_sim    = (const int*)d_in[28];
  const int* ee_idx    = (const int*)d_in[29];
  float* out = (float*)d_out;

  char* ws = (char*)d_ws;
  size_t off = 0;
  auto alloc = [&](size_t bytes) -> void* {
    off = (off + 255) & ~(size_t)255;
    void* p = ws + off;
    off += bytes;
    return p;
  };

  // ---- shared small + CSR + weight buffers (both paths) ----
  float* scal   = (float*)alloc(8 * 4);
  float* wv     = (float*)alloc(H * 4);
  float* pooled = (float*)alloc(H * 4);
  float* convbias = (float*)alloc(H * 4);
  float* parts  = (float*)alloc(64 * 4);
  float* scores = (float*)alloc(NW * 4);
  int* counts   = (int*)alloc(90000 * 4);
  int* offsb    = (int*)alloc(90004 * 4);
  int* cursor   = (int*)alloc(90000 * 4);
  int* ssrc     = (int*)alloc(800000 * 4);
  int* sij      = (int*)alloc(600000 * 4);
  float* WrSf   = (float*)alloc((size_t)NLAYER * HH * 4);
  float* WgSf   = (float*)alloc((size_t)NLAYER * HH * 4);
  float* bSf    = (float*)alloc((size_t)NLAYER * H * 4);

  // weight hi/lo (transposed) buffers
  u16 *wpw_h, *wpw_l, *wpow_h, *wpow_l, *wpoe_h, *wpoe_l, *wpe_h, *wpe_l;
  u16 *p1w_h, *p1w_l, *cwl_h, *cwl_l, *wrs_h, *wrs_l, *ewl_h, *ewl_l, *ewr_h, *ewr_l, *lw_h, *lw_l;
  wpw_h  = (u16*)alloc((size_t)HH * 2);     wpw_l  = (u16*)alloc((size_t)HH * 2);
  wpow_h = (u16*)alloc((size_t)HH * 2);     wpow_l = (u16*)alloc((size_t)HH * 2);
  wpoe_h = (u16*)alloc((size_t)HH * 2);     wpoe_l = (u16*)alloc((size_t)HH * 2);
  wpe_h  = (u16*)alloc((size_t)H * KECHP * 2); wpe_l = (u16*)alloc((size_t)H * KECHP * 2);
  p1w_h  = (u16*)alloc((size_t)4 * HH * 2); p1w_l  = (u16*)alloc((size_t)4 * HH * 2);
  cwl_h  = (u16*)alloc((size_t)12 * HH * 2); cwl_l = (u16*)alloc((size_t)12 * HH * 2);
  wrs_h  = (u16*)alloc((size_t)4 * HH * 2); wrs_l  = (u16*)alloc((size_t)4 * HH * 2);
  ewl_h  = (u16*)alloc((size_t)4 * HH * 2); ewl_l  = (u16*)alloc((size_t)4 * HH * 2);
  ewr_h  = (u16*)alloc((size_t)4 * HH * 2); ewr_l  = (u16*)alloc((size_t)4 * HH * 2);
  lw_h   = (u16*)alloc((size_t)256 * H * 2); lw_l  = (u16*)alloc((size_t)256 * H * 2);

  // persistent activations (ping set A)
  float* hwA   = (float*)alloc((size_t)NWP * H * 4);
  u16*   hwA_h = (u16*)alloc((size_t)NWP * H * 2);
  u16*   hwA_l = (u16*)alloc((size_t)NWP * H * 2);
  float* heA   = (float*)alloc((size_t)NEP * H * 4);
  u16*   heA_h = (u16*)alloc((size_t)NEP * H * 2);
  u16*   heA_l = (u16*)alloc((size_t)NEP * H * 2);

  // overlapped region: pre-phase arrays vs layer-phase arrays
  const size_t deadBase = (off + 255) & ~(size_t)255;
  // pre-phase
  off = deadBase;
  const int CHKP = 1056;  // max chunk Kpad
  u16* ch_h = (u16*)alloc((size_t)NEP * CHKP * 2);
  u16* ch_l = (u16*)alloc((size_t)NEP * CHKP * 2);
  u16* tp_h = (u16*)alloc((size_t)NEP * H * 2);
  u16* tp_l = (u16*)alloc((size_t)NEP * H * 2);
  u16* xw_h = (u16*)alloc((size_t)NWP * H * 2);
  u16* xw_l = (u16*)alloc((size_t)NWP * H * 2);
  const size_t preEnd = off;
  // layer-phase (aliases pre-phase)
  off = deadBase;
  float* hwB   = (float*)alloc((size_t)NWP * H * 4);
  u16*   hwB_h = (u16*)alloc((size_t)NWP * H * 2);
  u16*   hwB_l = (u16*)alloc((size_t)NWP * H * 2);
  float* heB   = (float*)alloc((size_t)NEP * H * 4);
  u16*   heB_h = (u16*)alloc((size_t)NEP * H * 2);
  u16*   heB_l = (u16*)alloc((size_t)NEP * H * 2);
  float* tmp   = (float*)alloc((size_t)NW * H * 4);   // h1
  u16* agw_h = (u16*)alloc((size_t)NWP * H * 2);
  u16* agw_l = (u16*)alloc((size_t)NWP * H * 2);
  u16* age_h = (u16*)alloc((size_t)NEP * H * 2);
  u16* age_l = (u16*)alloc((size_t)NEP * H * 2);
  const size_t layerEnd = off;
  const size_t need = (preEnd > layerEnd ? preEnd : layerEnd);

  float* maxv = scal; float* denom = scal + 1;
  dim3 eg((ER + 255) / 256), bg(256);

  // ---- CSR build (shared) ----
  hipMemsetAsync(counts, 0, 90000 * 4, stream);
  count_kernel<<<eg, bg, 0, stream>>>(ei_near + ER,  counts,          ER);
  count_kernel<<<eg, bg, 0, stream>>>(ei_close + ER, counts + 20000,  ER);
  count_kernel<<<eg, bg, 0, stream>>>(ei_sim + ER,   counts + 40000,  ER);
  count_kernel<<<eg, bg, 0, stream>>>(ee_idx + EE,   counts + 60000,  EE);
  scan_kernel<<<1, 1024, 0, stream>>>(counts,         offsb,          NW);
  scan_kernel<<<1, 1024, 0, stream>>>(counts + 20000, offsb + 20001,  NW);
  scan_kernel<<<1, 1024, 0, stream>>>(counts + 40000, offsb + 40002,  NW);
  scan_kernel<<<1, 1024, 0, stream>>>(counts + 60000, offsb + 60003,  NE);
  hipMemcpyAsync(cursor,         offsb,         20000 * 4, hipMemcpyDeviceToDevice, stream);
  hipMemcpyAsync(cursor + 20000, offsb + 20001, 20000 * 4, hipMemcpyDeviceToDevice, stream);
  hipMemcpyAsync(cursor + 40000, offsb + 40002, 20000 * 4, hipMemcpyDeviceToDevice, stream);
  hipMemcpyAsync(cursor + 60000, offsb + 60003, 30000 * 4, hipMemcpyDeviceToDevice, stream);
  fill_kernel<<<eg, bg, 0, stream>>>(ei_near,  ei_near + ER,  ij_near,  cursor,         ssrc,          sij,          ER);
  fill_kernel<<<eg, bg, 0, stream>>>(ei_close, ei_close + ER, ij_close, cursor + 20000, ssrc + ER,     sij + ER,     ER);
  fill_kernel<<<eg, bg, 0, stream>>>(ei_sim,   ei_sim + ER,   ij_sim,   cursor + 40000, ssrc + 2 * ER, sij + 2 * ER, ER);
  fill_kernel<<<eg, bg, 0, stream>>>(ee_idx,   ee_idx + EE,   nullptr,  cursor + 60000, ssrc + 3 * ER, nullptr,      EE);
  wsum_kernel<<<(NLAYER * HH + 255) / 256, 256, 0, stream>>>(convWr, convWg, convB, WrSf, WgSf, bSf);
  const int* offs_ee = offsb + 60003;

  if (need <= ws_size) {
    // ================= split-bf16 MFMA path =================
    auto cw = [&](const float* W, u16* Oh, u16* Ol, int K, int N, int Kpad, int Npad, int B) {
      dim3 g(Npad / 32, Kpad / 32, B), b(32, 8);
      convert_w<<<g, b, 0, stream>>>(W, Oh, Ol, K, N, Kpad, Npad);
    };
    auto cr = [&](const float* X, u16* Oh, u16* Ol, int M, int rs, int kOff, int kLen,
                  int Kpad, int Mpad) {
      int total = Mpad * (Kpad >> 3);
      convert_rows<<<(total + 255) / 256, 256, 0, stream>>>(X, Oh, Ol, M, rs, kOff, kLen, Kpad, Mpad);
    };
    auto mg = [&](int BETA, int LEAKY, int MODE, const u16* Ahh, const u16* All, int KaA,
                  const u16* Bhh, const u16* Bll, int KaB, int kBoff,
                  float* C, const float* bias, u16* Oh, u16* Ol, int M, int N, float scale) {
      dim3 g((N + 127) / 128, (M + 127) / 128), b(256);
#define MGCASE(B_, L_, M_) hipLaunchKernelGGL((mgemm<B_, L_, M_>), g, b, 0, stream, \
        Ahh, All, KaA, Bhh, Bll, KaB, kBoff, C, bias, Oh, Ol, M, N, scale)
      if      (BETA == 0 && LEAKY == 0 && MODE == 0) MGCASE(0, 0, 0);
      else if (BETA == 1 && LEAKY == 0 && MODE == 0) MGCASE(1, 0, 0);
      else if (BETA == 0 && LEAKY == 1 && MODE == 1) MGCASE(0, 1, 1);
      else if (BETA == 0 && LEAKY == 1 && MODE == 2) MGCASE(0, 1, 2);
      else if (BETA == 1 && LEAKY == 1 && MODE == 1) MGCASE(1, 1, 1);
      else if (BETA == 1 && LEAKY == 1 && MODE == 2) MGCASE(1, 1, 2);
#undef MGCASE
    };

    // weight conversions (transpose + hi/lo split)
    cw(Wpre_w,  wpw_h,  wpw_l,  512, 512, 512, 512, 1);
    cw(Wpost_w, wpow_h, wpow_l, 512, 512, 512, 512, 1);
    cw(Wpost_e, wpoe_h, wpoe_l, 512, 512, 512, 512, 1);
    cw(Wpre_e,  wpe_h,  wpe_l,  ECH, 512, KECHP, 512, 1);
    cw(p1W,  p1w_h, p1w_l, 512, 512, 512, 512, 4);
    cw(convWl, cwl_h, cwl_l, 512, 512, 512, 512, 12);
    cw(WrSf, wrs_h, wrs_l, 512, 512, 512, 512, 4);
    cw(eWl,  ewl_h, ewl_l, 512, 512, 512, 512, 4);
    cw(eWr,  ewr_h, ewr_l, 512, 512, 512, 512, 4);
    cw(linW, lw_h,  lw_l,  512, OUT_DIM, 512, 256, 1);

    // ---- pre-transforms ----
    cr(x_win, xw_h, xw_l, NW, MDIM, 0, MDIM, 512, NWP);
    mg(0, 1, 1, xw_h, xw_l, 512, wpw_h, wpw_l, 512, 0, nullptr, nullptr, tp_h, tp_l, NW, 512, 1.f);
    mg(0, 1, 2, tp_h, tp_l, 512, wpow_h, wpow_l, 512, 0, hwA, nullptr, hwA_h, hwA_l, NW, 512, 1.f);

    const int cstart[4] = {0, 1024, 2048, 3072};
    const int clen[4]   = {1024, 1024, 1024, ECH - 3072};
    const int ckpad[4]  = {1024, 1024, 1024, 1056};
    for (int c = 0; c < 4; c++) {
      cr(x_edge, ch_h, ch_l, NE, ECH, cstart[c], clen[c], ckpad[c], NEP);
      mg(c > 0 ? 1 : 0, c == 3 ? 1 : 0, c == 3 ? 1 : 0,
         ch_h, ch_l, ckpad[c], wpe_h, wpe_l, KECHP, cstart[c],
         heA, nullptr, tp_h, tp_l, NE, 512, 1.f);
    }
    mg(0, 1, 2, tp_h, tp_l, 512, wpoe_h, wpoe_l, 512, 0, heA, nullptr, heA_h, heA_l, NE, 512, 1.f);

    float* hw = hwA;  u16* hw_h = hwA_h;  u16* hw_l = hwA_l;
    float* he = heA;  u16* he_h = heA_h;  u16* he_l = heA_l;
    float* hwn = hwB; u16* hwn_h = hwB_h; u16* hwn_l = hwB_l;
    float* hen = heB; u16* hen_h = heB_h; u16* hen_l = heB_l;

    for (int l = 0; l < NLAYER; l++) {
      // pooling
      mg(0, 0, 0, hw_h, hw_l, 512, p1w_h + (size_t)l * HH, p1w_l + (size_t)l * HH, 512, 0,
         tmp, p1b + l * H, nullptr, nullptr, NW, 512, 1.f);
      pool_qk_kernel<<<1, 512, 0, stream>>>(pS + l * H, pWq + (size_t)l * HH, pWk + (size_t)l * HH, wv);
      scores_kernel<<<NW / 4, 256, 0, stream>>>(tmp, wv, scores, NW);
      max_part_kernel<<<40, 256, 0, stream>>>(scores, parts, NW);
      max_fin_kernel<<<1, 512, 0, stream>>>(parts, 40, maxv, denom, pooled);
      expsum_kernel<<<40, 256, 0, stream>>>(scores, maxv, denom, NW);
      pool_weighted_kernel<<<(NW + 127) / 128, 256, 0, stream>>>(tmp, scores, pooled, NW);
      pool_fin_kernel<<<1, 512, 0, stream>>>(pooled, denom, pWv + (size_t)l * HH,
          p2W + (size_t)l * HH, p2b + l * H, WgSf + (size_t)l * HH, bSf + l * H, convbias);

      // window conv
      for (int r = 0; r < 3; r++) {
        agg_win_bf<<<NWP, 128, 0, stream>>>(hw, he, offsb + r * 20001, ssrc + (size_t)r * ER,
                                            sij + (size_t)r * ER, agw_h, agw_l, NW);
        mg(r > 0 ? 1 : 0, 0, 0, agw_h, agw_l, 512,
           cwl_h + ((size_t)l * 3 + r) * HH, cwl_l + ((size_t)l * 3 + r) * HH, 512, 0,
           hwn, r == 0 ? convbias : nullptr, nullptr, nullptr, NW, 512, 1.f);
      }
      mg(1, 1, 2, hw_h, hw_l, 512, wrs_h + (size_t)l * HH, wrs_l + (size_t)l * HH, 512, 0,
         hwn, nullptr, hwn_h, hwn_l, NW, 512, 1.f / 3.f);

      // edge conv
      agg_edge_bf<<<NEP, 128, 0, stream>>>(he, offs_ee, ssrc + 3 * (size_t)ER, age_h, age_l, NE);
      mg(0, 0, 0, age_h, age_l, 512, ewl_h + (size_t)l * HH, ewl_l + (size_t)l * HH, 512, 0,
         hen, eB + l * H, nullptr, nullptr, NE, 512, 1.f);
      mg(1, 1, 2, he_h, he_l, 512, ewr_h + (size_t)l * HH, ewr_l + (size_t)l * HH, 512, 0,
         hen, nullptr, hen_h, hen_l, NE, 512, 1.f);

      { float* t = hw; hw = hwn; hwn = t; }
      { u16* t = hw_h; hw_h = hwn_h; hwn_h = t; }
      { u16* t = hw_l; hw_l = hwn_l; hwn_l = t; }
      { float* t = he; he = hen; hen = t; }
      { u16* t = he_h; he_h = hen_h; hen_h = t; }
      { u16* t = he_l; he_l = hen_l; hen_l = t; }
    }

    mg(0, 0, 0, hw_h, hw_l, 512, lw_h, lw_l, 512, 0, out, linb, nullptr, nullptr, NW, OUT_DIM, 1.f);
  } else {
    // ================= fallback fp32 path (round-1) =================
    off = deadBase;
    float* hw    = (float*)alloc((size_t)NW * H * 4);
    float* hwacc = (float*)alloc((size_t)NW * H * 4);
    float* he    = (float*)alloc((size_t)NE * H * 4);
    float* heacc = (float*)alloc((size_t)NE * H * 4);
    float* ftmp  = (float*)alloc((size_t)NE * H * 4);
    float* aggw  = (float*)alloc((size_t)NW * H * 4);

    auto gemm = [&](int beta, int lk, const float* A, const float* B, float* C,
                    const float* bias, int M, int N, int K, float scale) {
      dim3 g((N + BN - 1) / BN, (M + BM - 1) / BM);
      if (!beta && !lk) hipLaunchKernelGGL((gemm_kernel<0,0>), g, dim3(256), 0, stream, A, B, C, bias, M, N, K, scale);
      else if (!beta)   hipLaunchKernelGGL((gemm_kernel<0,1>), g, dim3(256), 0, stream, A, B, C, bias, M, N, K, scale);
      else if (!lk)     hipLaunchKernelGGL((gemm_kernel<1,0>), g, dim3(256), 0, stream, A, B, C, bias, M, N, K, scale);
      else              hipLaunchKernelGGL((gemm_kernel<1,1>), g, dim3(256), 0, stream, A, B, C, bias, M, N, K, scale);
    };

    gemm(0, 1, x_win,  Wpre_w,  ftmp, nullptr, NW, H, MDIM, 1.f);
    gemm(0, 1, ftmp,   Wpost_w, hw,   nullptr, NW, H, H,    1.f);
    gemm(0, 1, x_edge, Wpre_e,  ftmp, nullptr, NE, H, ECH,  1.f);
    gemm(0, 1, ftmp,   Wpost_e, he,   nullptr, NE, H, H,    1.f);

    for (int l = 0; l < NLAYER; l++) {
      gemm(0, 0, hw, p1W + (size_t)l * HH, ftmp, p1b + l * H, NW, H, H, 1.f);
      pool_qk_kernel<<<1, 512, 0, stream>>>(pS + l * H, pWq + (size_t)l * HH, pWk + (size_t)l * HH, wv);
      scores_kernel<<<NW / 4, 256, 0, stream>>>(ftmp, wv, scores, NW);
      max_part_kernel<<<40, 256, 0, stream>>>(scores, parts, NW);
      max_fin_kernel<<<1, 512, 0, stream>>>(parts, 40, maxv, denom, pooled);
      expsum_kernel<<<40, 256, 0, stream>>>(scores, maxv, denom, NW);
      pool_weighted_kernel<<<(NW + 127) / 128, 256, 0, stream>>>(ftmp, scores, pooled, NW);
      pool_fin_kernel<<<1, 512, 0, stream>>>(pooled, denom, pWv + (size_t)l * HH,
          p2W + (size_t)l * HH, p2b + l * H, WgSf + (size_t)l * HH, bSf + l * H, convbias);

      for (int r = 0; r < 3; r++) {
        agg_win_f32<<<NW, 128, 0, stream>>>(hw, he, offsb + r * 20001, ssrc + (size_t)r * ER,
                                            sij + (size_t)r * ER, aggw);
        if (r == 0) gemm(0, 0, aggw, convWl + ((size_t)l * 3 + r) * HH, hwacc, convbias, NW, H, H, 1.f);
        else        gemm(1, 0, aggw, convWl + ((size_t)l * 3 + r) * HH, hwacc, nullptr,  NW, H, H, 1.f);
      }
      gemm(1, 1, hw, WrSf + (size_t)l * HH, hwacc, nullptr, NW, H, H, 1.f / 3.f);

      agg_edge_f32<<<NE, 128, 0, stream>>>(he, offs_ee, ssrc + 3 * (size_t)ER, ftmp);
      gemm(0, 0, ftmp, eWl + (size_t)l * HH, heacc, eB + l * H, NE, H, H, 1.f);
      gemm(1, 1, he,   eWr + (size_t)l * HH, heacc, nullptr,    NE, H, H, 1.f);

      { float* t = hw; hw = hwacc; hwacc = t; }
      { float* t = he; he = heacc; heacc = t; }
    }
    gemm(0, 0, hw, linW, out, linb, NW, OUT_DIM, H, 1.f);
  }
}